// Round 1
// baseline (149.449 us; speedup 1.0000x reference)
//
#include <hip/hip_runtime.h>

#define Bn 4
#define Tn 512
#define Mn 16
#define Dn 128
#define Pn 128
#define Hn 4
#define SCALE 0.08838834764831845f  // 1 / (2*sqrt(32))

typedef unsigned short u16;
typedef unsigned int u32;
typedef short s16;
typedef __attribute__((ext_vector_type(8))) s16 bf16x8;   // 8 bf16 = 4 VGPRs
typedef __attribute__((ext_vector_type(4))) float f32x4;  // MFMA C/D

__device__ __forceinline__ u16 f2b(float f) {  // fp32 -> bf16 rne
  u32 x; __builtin_memcpy(&x, &f, 4);
  x += 0x7fffu + ((x >> 16) & 1u);
  return (u16)(x >> 16);
}
__device__ __forceinline__ u32 pack2(float a, float b) {
  return (u32)f2b(a) | ((u32)f2b(b) << 16);
}
__device__ __forceinline__ bf16x8 ld8(const u16* p) {  // 16B frag load
  bf16x8 r; __builtin_memcpy(&r, p, 16); return r;
}
__device__ __forceinline__ f32x4 mfma16(bf16x8 a, bf16x8 b, f32x4 c) {
  // D rows (quad*4+reg) <- a's m-index; D cols (lane&15) <- b's n-index
  return __builtin_amdgcn_mfma_f32_16x16x32_bf16(a, b, c, 0, 0, 0);
}

// ---------------------------------------------------------------- lengths ---
__global__ void lengths_kernel(const void* __restrict__ mask, int* __restrict__ len_out) {
  const int b = blockIdx.x;
  __shared__ int cnt[256];
  const u32 w0 = ((const u32*)mask)[0];
  const int mode = (w0 == 1u) ? 0 : (w0 == 0x3F800000u) ? 1
                 : (w0 == 0x3F803F80u) ? 2 : 3;
  int c = 0;
  for (int t = threadIdx.x; t < Tn; t += 256) {
    const size_t idx = ((size_t)b * Tn + t) * Mn;
    int nz;
    if (mode == 0)      nz = (((const int*)mask)[idx] != 0);
    else if (mode == 1) nz = (((const u32*)mask)[idx] != 0u);
    else if (mode == 2) nz = (((const u16*)mask)[idx] != 0);
    else                nz = (((const unsigned char*)mask)[idx] != 0);
    c += nz;
  }
  cnt[threadIdx.x] = c;
  __syncthreads();
  for (int s = 128; s > 0; s >>= 1) {
    if (threadIdx.x < (unsigned)s) cnt[threadIdx.x] += cnt[threadIdx.x + s];
    __syncthreads();
  }
  if (threadIdx.x == 0) len_out[b] = cnt[0];
}

// --------------------------------------------------------- projection MFMA ---
// Block = (rowtile 128, m, tsel). K-split staging (two 64-d halves) keeps LDS
// at 36.9KB -> 4 blocks/CU. Outputs: Qa/Ka/Qb/Kb as [bmh][t][32] bf16 (SCALE
// folded into Qa/Qb), V transposed as Vt [bmh][e][t] via packed 8B stores.
__global__ __launch_bounds__(256) void proj_mfma(
    const float* __restrict__ inp, const float* __restrict__ pos,
    const float* __restrict__ Wq, const float* __restrict__ Bq,
    const float* __restrict__ Wk, const float* __restrict__ Bk,
    const float* __restrict__ Wv, const float* __restrict__ Bv,
    const float* __restrict__ Wqt, const float* __restrict__ Bqt,
    const float* __restrict__ Wkt, const float* __restrict__ Bkt,
    u16* __restrict__ Qa, u16* __restrict__ Ka, u16* __restrict__ Qb,
    u16* __restrict__ Kb, u16* __restrict__ Vt) {
  const int tid = threadIdx.x;
  const int bid = blockIdx.x;
  const int tsel = bid % 5;
  const int m = (bid / 5) % Mn;
  const int rt0 = (bid / (5 * Mn)) * 128;

  const float* W; const float* Bb; int usepos, doscale;
  u16* dst;
  switch (tsel) {
    case 0:  W = Wq;  Bb = Bq;  usepos = 0; doscale = 1; dst = Qa; break;
    case 1:  W = Wk;  Bb = Bk;  usepos = 0; doscale = 0; dst = Ka; break;
    case 2:  W = Wv;  Bb = Bv;  usepos = 0; doscale = 0; dst = Vt; break;
    case 3:  W = Wqt; Bb = Bqt; usepos = 1; doscale = 1; dst = Qb; break;
    default: W = Wkt; Bb = Bkt; usepos = 1; doscale = 0; dst = Kb; break;
  }
  const float* A = usepos ? pos : inp;

  __shared__ __align__(16) u16 Xs[128 * 72];   // 18.4KB (64-d half, pad 8)
  __shared__ __align__(16) u16 Ws2[128 * 72];  // 18.4KB

  const int wv = tid >> 6, lane = tid & 63;
  const int quad = lane >> 4, l16 = lane & 15;

  f32x4 acc[2][8];
#pragma unroll
  for (int qs = 0; qs < 2; ++qs)
#pragma unroll
    for (int n = 0; n < 8; ++n) acc[qs][n] = (f32x4){0.f, 0.f, 0.f, 0.f};

  for (int kh = 0; kh < 2; ++kh) {
    for (int idx = tid; idx < 128 * 16; idx += 256) {
      const int row = idx >> 4, c4 = (idx & 15) * 4, col = kh * 64 + c4;
      const size_t sx = usepos ? ((size_t)(rt0 + row) * Dn + col)
                               : (((size_t)(rt0 + row) * Mn + m) * Dn + col);
      const float4 x = *(const float4*)(A + sx);
      ushort4 xh; xh.x = f2b(x.x); xh.y = f2b(x.y); xh.z = f2b(x.z); xh.w = f2b(x.w);
      *(ushort4*)&Xs[row * 72 + c4] = xh;
      const float4 w = *(const float4*)(W + ((size_t)m * Pn + row) * Dn + col);
      ushort4 wh; wh.x = f2b(w.x); wh.y = f2b(w.y); wh.z = f2b(w.z); wh.w = f2b(w.w);
      *(ushort4*)&Ws2[row * 72 + c4] = wh;
    }
    __syncthreads();
#pragma unroll
    for (int kc = 0; kc < 2; ++kc) {
      const int ko = kc * 32 + quad * 8;
      const bf16x8 a0 = ld8(&Xs[(wv * 32 + l16) * 72 + ko]);
      const bf16x8 a1 = ld8(&Xs[(wv * 32 + 16 + l16) * 72 + ko]);
#pragma unroll
      for (int n = 0; n < 8; ++n) {
        const bf16x8 bn = ld8(&Ws2[(n * 16 + l16) * 72 + ko]);
        acc[0][n] = mfma16(a0, bn, acc[0][n]);
        acc[1][n] = mfma16(a1, bn, acc[1][n]);
      }
    }
    __syncthreads();
  }

  const int b = rt0 >> 9;            // rowtile never crosses a batch boundary
  const int tl0 = (rt0 & (Tn - 1)) + wv * 32;
#pragma unroll
  for (int n = 0; n < 8; ++n) {
    const int h = n >> 1, e = (n & 1) * 16 + l16;
    const float bias = Bb[m * Pn + n * 16 + l16];
    const int bmh = (b * Mn + m) * Hn + h;
    if (tsel != 2) {
#pragma unroll
      for (int qs = 0; qs < 2; ++qs)
#pragma unroll
        for (int reg = 0; reg < 4; ++reg) {
          const int t = tl0 + qs * 16 + quad * 4 + reg;
          float v = acc[qs][n][reg] + bias;
          if (doscale) v *= SCALE;
          dst[((size_t)bmh * Tn + t) * 32 + e] = f2b(v);
        }
    } else {
      const size_t rowv = ((size_t)bmh * 32 + e) * Tn;
#pragma unroll
      for (int qs = 0; qs < 2; ++qs) {
        const int t0 = tl0 + qs * 16 + quad * 4;
        uint2 d;
        d.x = pack2(acc[qs][n][0] + bias, acc[qs][n][1] + bias);
        d.y = pack2(acc[qs][n][2] + bias, acc[qs][n][3] + bias);
        *(uint2*)&dst[rowv + t0] = d;
      }
    }
  }
}

// ------------------------------------------------------- attention (flash) ---
// Wave-autonomous: wave = 32 q-rows of one (b,m,h). S^T = Khat.Qhat^T so C
// cols = q (lane&15): softmax = in-lane + xor16/xor32 shuffles; P written as
// packed 8B runs to a PRIVATE per-wave LDS slab (no __syncthreads anywhere);
// O^T = V^T.P keeps q on l16. K/Q/V frags load straight from global (L2).
//
// LOAD BALANCE: causal work per q-tile qt is ceil((qt+1)/2) key-chunk
// iterations (1..8). Each wave processes the PAIR (j, 15-j) sequentially:
// ceil((j+1)/2) + ceil((16-j)/2) == 9 for all j, so every wave/block/CU does
// identical work by construction (previously 1/4 of the CUs carried qt=12..15
// exclusively -> ~1.65x critical-path stretch). 2048 waves, 128-thr blocks,
// 8 blocks/CU (LDS 9.2KB/block), still 16 waves/CU @ <=128 VGPR.
__global__ __launch_bounds__(128, 4) void attn_flash(
    const u16* __restrict__ Qa, const u16* __restrict__ Ka,
    const u16* __restrict__ Qb, const u16* __restrict__ Kb,
    const u16* __restrict__ Vt, const int* __restrict__ lens,
    float* __restrict__ out) {
  __shared__ __align__(16) u16 Ps[2 * 32 * 72];  // 9.2KB, per-wave slabs

  const int tid = threadIdx.x;
  const int wv = tid >> 6, lane = tid & 63;
  const int quad = lane >> 4, l16 = lane & 15;

  const int wu = blockIdx.x * 2 + wv;      // 0..2047
  const int pair = wu & 7;                 // q-tile pair (pair, 15-pair)
  const int bmh = wu >> 3;
  const int b = bmh >> 6;                  // Mn*Hn = 64
  const int len = lens[b];

  const size_t rowbase = (size_t)bmh * Tn;
  const size_t vbase = (size_t)bmh * 32 * Tn;
  u16* myPs = &Ps[wv * 32 * 72];
  const int mm = (bmh >> 2) & (Mn - 1);
  const int h = bmh & (Hn - 1);

#pragma unroll 1
  for (int half = 0; half < 2; ++half) {
    const int qt = half ? (15 - pair) : pair;
    const int q0 = qt * 32;

    bf16x8 qf[2][2];
#pragma unroll
    for (int qs = 0; qs < 2; ++qs) {
      const size_t r = (rowbase + q0 + qs * 16 + l16) * 32 + quad * 8;
      qf[qs][0] = ld8(Qa + r);
      qf[qs][1] = ld8(Qb + r);
    }

    f32x4 O[2][2];  // [qs][es], D rows = e (quad*4+reg), cols = q (l16)
#pragma unroll
    for (int qs = 0; qs < 2; ++qs)
#pragma unroll
      for (int es = 0; es < 2; ++es) O[qs][es] = (f32x4){0.f, 0.f, 0.f, 0.f};
    float mrow[2] = {-1e30f, -1e30f}, lsum[2] = {0.f, 0.f};

    const int s_hi = min(q0 + 32, len);    // len >= T/2 >= 1
    for (int s0 = 0; s0 < s_hi; s0 += 64) {
      // S^T tiles: rows = keys (st*16 chunks), cols = q. Always 4 tiles
      // (loads stay in-bounds: s0+63 <= 511); masking handles validity.
      f32x4 S[2][4];
#pragma unroll
      for (int st = 0; st < 4; ++st) {
        const size_t kr = (rowbase + s0 + st * 16 + l16) * 32 + quad * 8;
        const bf16x8 k0 = ld8(Ka + kr);
        const bf16x8 k1 = ld8(Kb + kr);
#pragma unroll
        for (int qs = 0; qs < 2; ++qs)
          S[qs][st] = mfma16(k1, qf[qs][1],
                             mfma16(k0, qf[qs][0], (f32x4){0.f, 0.f, 0.f, 0.f}));
      }

#pragma unroll
      for (int qs = 0; qs < 2; ++qs) {
        const int q = q0 + qs * 16 + l16;
        const int qcap = min(q, len - 1);  // valid <=> s <= qcap
        const int sb = s0 + quad * 4;
        float cmax = -1e30f;
#pragma unroll
        for (int st = 0; st < 4; ++st)
#pragma unroll
          for (int reg = 0; reg < 4; ++reg) {
            const int s = sb + st * 16 + reg;
            const float v = (s <= qcap) ? S[qs][st][reg] : -1e30f;
            S[qs][st][reg] = v;
            cmax = fmaxf(cmax, v);
          }
        cmax = fmaxf(cmax, __shfl_xor(cmax, 16));
        cmax = fmaxf(cmax, __shfl_xor(cmax, 32));
        const float mnew = fmaxf(mrow[qs], cmax);  // finite: every chunk has a valid key
        const float alpha = __expf(mrow[qs] - mnew);
        mrow[qs] = mnew;
        float rsum = 0.f;
        u32 pk[4][2];
#pragma unroll
        for (int st = 0; st < 4; ++st) {
          const float p0 = __expf(S[qs][st][0] - mnew);
          const float p1 = __expf(S[qs][st][1] - mnew);
          const float p2 = __expf(S[qs][st][2] - mnew);
          const float p3 = __expf(S[qs][st][3] - mnew);
          rsum += (p0 + p1) + (p2 + p3);
          pk[st][0] = pack2(p0, p1);
          pk[st][1] = pack2(p2, p3);
        }
        rsum += __shfl_xor(rsum, 16);
        rsum += __shfl_xor(rsum, 32);
        lsum[qs] = lsum[qs] * alpha + rsum;
#pragma unroll
        for (int es = 0; es < 2; ++es)
#pragma unroll
          for (int reg = 0; reg < 4; ++reg) O[qs][es][reg] *= alpha;
        // P -> private LDS slab (8B packed runs; same-wave ordering via lgkmcnt)
#pragma unroll
        for (int st = 0; st < 4; ++st) {
          uint2 d; d.x = pk[st][0]; d.y = pk[st][1];
          *(uint2*)&myPs[(qs * 16 + l16) * 72 + st * 16 + quad * 4] = d;
        }
      }

      // O^T += V^T . P
#pragma unroll
      for (int kc = 0; kc < 2; ++kc) {
        const int ko = kc * 32 + quad * 8;
        const bf16x8 pf0 = ld8(&myPs[l16 * 72 + ko]);
        const bf16x8 pf1 = ld8(&myPs[(16 + l16) * 72 + ko]);
        const bf16x8 vf0 = ld8(Vt + vbase + (size_t)l16 * Tn + s0 + ko);
        const bf16x8 vf1 = ld8(Vt + vbase + (size_t)(16 + l16) * Tn + s0 + ko);
        O[0][0] = mfma16(vf0, pf0, O[0][0]);
        O[0][1] = mfma16(vf1, pf0, O[0][1]);
        O[1][0] = mfma16(vf0, pf1, O[1][0]);
        O[1][1] = mfma16(vf1, pf1, O[1][1]);
      }
    }

    // epilogue: lane q = qs*16+l16 (matches state), e = es*16+quad*4+reg
#pragma unroll
    for (int qs = 0; qs < 2; ++qs) {
      const float linv = 1.0f / lsum[qs];
      const int t = q0 + qs * 16 + l16;
      const size_t ob = (((size_t)b * Tn + t) * Mn + mm) * Pn + h * 32 + quad * 4;
#pragma unroll
      for (int es = 0; es < 2; ++es) {
        float4 o;
        o.x = O[qs][es][0] * linv; o.y = O[qs][es][1] * linv;
        o.z = O[qs][es][2] * linv; o.w = O[qs][es][3] * linv;
        *(float4*)&out[ob + es * 16] = o;
      }
    }
  }
}

// ------------------------------------------------------------------ launch ---
extern "C" void kernel_launch(void* const* d_in, const int* in_sizes, int n_in,
                              void* d_out, int out_size, void* d_ws, size_t ws_size,
                              hipStream_t stream) {
  const float* inp = (const float*)d_in[0];
  const float* pos = (const float*)d_in[1];
  const void* mask = d_in[2];
  const float* Wq  = (const float*)d_in[3];
  const float* Bq  = (const float*)d_in[4];
  const float* Wk  = (const float*)d_in[5];
  const float* Bk  = (const float*)d_in[6];
  const float* Wv  = (const float*)d_in[7];
  const float* Bv  = (const float*)d_in[8];
  const float* Wqt = (const float*)d_in[9];
  const float* Bqt = (const float*)d_in[10];
  const float* Wkt = (const float*)d_in[11];
  const float* Bkt = (const float*)d_in[12];
  float* out = (float*)d_out;

  const size_t nA = (size_t)Bn * Mn * Hn * Tn * 32;  // 4.19M elems per array
  u16* Qa = (u16*)d_ws;
  u16* Ka = Qa + nA;
  u16* Qb = Ka + nA;
  u16* Kb = Qb + nA;
  u16* Vt = Kb + nA;
  int* lens = (int*)(Vt + nA);

  lengths_kernel<<<Bn, 256, 0, stream>>>(mask, lens);
  proj_mfma<<<(Bn * Tn / 128) * Mn * 5, 256, 0, stream>>>(
      inp, pos, Wq, Bq, Wk, Bk, Wv, Bv, Wqt, Bqt, Wkt, Bkt, Qa, Ka, Qb, Kb, Vt);
  attn_flash<<<(Bn * Mn * Hn * 8) / 2, 128, 0, stream>>>(
      Qa, Ka, Qb, Kb, Vt, lens, out);
}

// Round 2
// 147.680 us; speedup vs baseline: 1.0120x; 1.0120x over previous
//
#include <hip/hip_runtime.h>

#define Bn 4
#define Tn 512
#define Mn 16
#define Dn 128
#define Pn 128
#define Hn 4
#define SCALE 0.08838834764831845f  // 1 / (2*sqrt(32))

typedef unsigned short u16;
typedef unsigned int u32;
typedef short s16;
typedef __attribute__((ext_vector_type(8))) s16 bf16x8;   // 8 bf16 = 4 VGPRs
typedef __attribute__((ext_vector_type(4))) float f32x4;  // MFMA C/D

#define NWE (Mn * Pn * Dn)  // 262144 elems per weight tensor

__device__ __forceinline__ u16 f2b(float f) {  // fp32 -> bf16 rne
  u32 x; __builtin_memcpy(&x, &f, 4);
  x += 0x7fffu + ((x >> 16) & 1u);
  return (u16)(x >> 16);
}
__device__ __forceinline__ u32 pack2(float a, float b) {
  return (u32)f2b(a) | ((u32)f2b(b) << 16);
}
__device__ __forceinline__ bf16x8 ld8(const u16* p) {  // 16B frag load
  bf16x8 r; __builtin_memcpy(&r, p, 16); return r;
}
__device__ __forceinline__ f32x4 mfma16(bf16x8 a, bf16x8 b, f32x4 c) {
  // D rows (quad*4+reg) <- a's row index (l16 at load); cols (l16) <- b's row
  return __builtin_amdgcn_mfma_f32_16x16x32_bf16(a, b, c, 0, 0, 0);
}

// ------------------------------------------------------------------- prep ---
// One pass: lengths (blocks 0..3) + f32->bf16 conversion of inp/pos/weights.
// All conversions happen exactly once here (previously pos was reconverted
// 32x, each W 16x, inp 3x inside proj's staging loop).
__global__ __launch_bounds__(256) void prep(
    const void* __restrict__ mask, const float* __restrict__ inp,
    const float* __restrict__ pos, const float* __restrict__ Wq,
    const float* __restrict__ Wk, const float* __restrict__ Wv,
    const float* __restrict__ Wqt, const float* __restrict__ Wkt,
    int* __restrict__ lens, u16* __restrict__ Xb, u16* __restrict__ Pb,
    u16* __restrict__ Wb) {
  if (blockIdx.x < Bn) {  // fold lengths in (saves a serialized launch)
    const int b = blockIdx.x;
    __shared__ int cnt[256];
    const u32 w0 = ((const u32*)mask)[0];
    const int mode = (w0 == 1u) ? 0 : (w0 == 0x3F800000u) ? 1
                   : (w0 == 0x3F803F80u) ? 2 : 3;
    int c = 0;
    for (int t = threadIdx.x; t < Tn; t += 256) {
      const size_t idx = ((size_t)b * Tn + t) * Mn;
      int nz;
      if (mode == 0)      nz = (((const int*)mask)[idx] != 0);
      else if (mode == 1) nz = (((const u32*)mask)[idx] != 0u);
      else if (mode == 2) nz = (((const u16*)mask)[idx] != 0);
      else                nz = (((const unsigned char*)mask)[idx] != 0);
      c += nz;
    }
    cnt[threadIdx.x] = c;
    __syncthreads();
    for (int s = 128; s > 0; s >>= 1) {
      if (threadIdx.x < (unsigned)s) cnt[threadIdx.x] += cnt[threadIdx.x + s];
      __syncthreads();
    }
    if (threadIdx.x == 0) lens[b] = cnt[0];
  }

  // unit = 8 elems (2x float4 load -> 1x 16B store)
  const int NI8 = Bn * Tn * Mn * Dn / 8;  // 524288
  const int NP8 = Bn * Tn * Dn / 8;       // 32768
  const int NW8 = NWE / 8;                // 32768
  const int total = NI8 + NP8 + 5 * NW8;  // 720896
  for (int u = blockIdx.x * 256 + threadIdx.x; u < total; u += gridDim.x * 256) {
    const float* s; u16* d; int off;
    if (u < NI8) { s = inp; d = Xb; off = u; }
    else if (u < NI8 + NP8) { s = pos; d = Pb; off = u - NI8; }
    else {
      const int r = u - NI8 - NP8;
      const int w = r >> 15; off = r & (NW8 - 1);
      switch (w) {
        case 0:  s = Wq;  d = Wb;            break;
        case 1:  s = Wk;  d = Wb + NWE;      break;
        case 2:  s = Wv;  d = Wb + 2 * NWE;  break;
        case 3:  s = Wqt; d = Wb + 3 * NWE;  break;
        default: s = Wkt; d = Wb + 4 * NWE;  break;
      }
    }
    const float4 a0 = *(const float4*)(s + (size_t)off * 8);
    const float4 a1 = *(const float4*)(s + (size_t)off * 8 + 4);
    uint4 dd;
    dd.x = pack2(a0.x, a0.y); dd.y = pack2(a0.z, a0.w);
    dd.z = pack2(a1.x, a1.y); dd.w = pack2(a1.z, a1.w);
    *(uint4*)(d + (size_t)off * 8) = dd;
  }
}

// --------------------------------------------------------- projection MFMA ---
// Block = (rowtile 128, m, tsel). Pure-bf16 staging: batched 16B loads into
// registers (all 8 in flight before any wait), then 16B LDS writes. No f2b in
// the hot path. Pad-72 rows keep all fragment reads 2-way (free).
// Operand orientation per tsel:
//   tsel!=2 (Q/K/Qb/Kb): A=W rows(p), B=X rows(t) -> lane holds 4 consecutive
//     p at fixed t -> packed uint2 stores into [bmh][t][32]. h == wave id.
//   tsel==2 (V): A=X rows(t), B=W rows(p) -> lane holds 4 consecutive t at
//     fixed e -> packed uint2 stores into Vt [bmh][e][t] (as before).
__global__ __launch_bounds__(256) void proj_mfma(
    const u16* __restrict__ Xb, const u16* __restrict__ Pb,
    const u16* __restrict__ Wb,
    const float* __restrict__ Bq, const float* __restrict__ Bk,
    const float* __restrict__ Bv, const float* __restrict__ Bqt,
    const float* __restrict__ Bkt,
    u16* __restrict__ Qa, u16* __restrict__ Ka, u16* __restrict__ Qb,
    u16* __restrict__ Kb, u16* __restrict__ Vt) {
  const int tid = threadIdx.x;
  const int bid = blockIdx.x;
  const int tsel = bid % 5;
  const int m = (bid / 5) % Mn;
  const int rt0 = (bid / (5 * Mn)) * 128;

  const float* Bb; int usepos, doscale; u16* dst;
  switch (tsel) {
    case 0:  Bb = Bq;  usepos = 0; doscale = 1; dst = Qa; break;
    case 1:  Bb = Bk;  usepos = 0; doscale = 0; dst = Ka; break;
    case 2:  Bb = Bv;  usepos = 0; doscale = 0; dst = Vt; break;
    case 3:  Bb = Bqt; usepos = 1; doscale = 1; dst = Qb; break;
    default: Bb = Bkt; usepos = 1; doscale = 0; dst = Kb; break;
  }
  const u16* A = usepos ? Pb : Xb;
  const u16* Wsrc = Wb + (size_t)tsel * NWE + (size_t)m * Pn * Dn;

  __shared__ __align__(16) u16 Xs[128 * 72];   // 18.4KB (64-d half, pad 8)
  __shared__ __align__(16) u16 Ws2[128 * 72];  // 18.4KB

  const int wv = tid >> 6, lane = tid & 63;
  const int quad = lane >> 4, l16 = lane & 15;

  f32x4 acc[2][8];
#pragma unroll
  for (int i = 0; i < 2; ++i)
#pragma unroll
    for (int n = 0; n < 8; ++n) acc[i][n] = (f32x4){0.f, 0.f, 0.f, 0.f};

  // orientation select: V uses A=X,B=W; others A=W,B=X (epilogue differs)
  const u16* Als = (tsel == 2) ? Xs : Ws2;
  const u16* Bls = (tsel == 2) ? Ws2 : Xs;

  for (int kh = 0; kh < 2; ++kh) {
    // stage 128x64 bf16 halves of X and W: 4x16B chunks each per thread,
    // all 8 global loads issued before LDS writes (single vmcnt drain).
    bf16x8 xr[4], wr[4];
#pragma unroll
    for (int it = 0; it < 4; ++it) {
      const int c = tid + it * 256;
      const int row = c >> 3, c8 = (c & 7) * 8, col = kh * 64 + c8;
      const size_t sx = usepos ? ((size_t)(rt0 + row) * Dn + col)
                               : (((size_t)(rt0 + row) * Mn + m) * Dn + col);
      xr[it] = ld8(A + sx);
    }
#pragma unroll
    for (int it = 0; it < 4; ++it) {
      const int c = tid + it * 256;
      const int row = c >> 3, c8 = (c & 7) * 8, col = kh * 64 + c8;
      wr[it] = ld8(Wsrc + (size_t)row * Dn + col);
    }
    if (kh) __syncthreads();  // previous half's reads done before overwrite
#pragma unroll
    for (int it = 0; it < 4; ++it) {
      const int c = tid + it * 256;
      const int row = c >> 3, c8 = (c & 7) * 8;
      *(bf16x8*)&Xs[row * 72 + c8] = xr[it];
    }
#pragma unroll
    for (int it = 0; it < 4; ++it) {
      const int c = tid + it * 256;
      const int row = c >> 3, c8 = (c & 7) * 8;
      *(bf16x8*)&Ws2[row * 72 + c8] = wr[it];
    }
    __syncthreads();
#pragma unroll
    for (int kc = 0; kc < 2; ++kc) {
      const int ko = kc * 32 + quad * 8;
      const bf16x8 a0 = ld8(&Als[(wv * 32 + l16) * 72 + ko]);
      const bf16x8 a1 = ld8(&Als[(wv * 32 + 16 + l16) * 72 + ko]);
#pragma unroll
      for (int n = 0; n < 8; ++n) {
        const bf16x8 bn = ld8(&Bls[(n * 16 + l16) * 72 + ko]);
        acc[0][n] = mfma16(a0, bn, acc[0][n]);
        acc[1][n] = mfma16(a1, bn, acc[1][n]);
      }
    }
    if (kh == 0) __syncthreads();
  }

  const int b = rt0 >> 9;            // rowtile never crosses a batch boundary
  const int tb = rt0 & (Tn - 1);

  if (tsel == 2) {
    // V: acc[qs][n] -> rows t = tb + wv*32 + qs*16 + quad*4 + reg, col e
    const int tl0 = tb + wv * 32;
#pragma unroll
    for (int n = 0; n < 8; ++n) {
      const int h = n >> 1, e = (n & 1) * 16 + l16;
      const float bias = Bb[m * Pn + n * 16 + l16];
      const int bmh = (b * Mn + m) * Hn + h;
      const size_t rowv = ((size_t)bmh * 32 + e) * Tn;
#pragma unroll
      for (int qs = 0; qs < 2; ++qs) {
        const int t0 = tl0 + qs * 16 + quad * 4;
        uint2 d;
        d.x = pack2(acc[qs][n][0] + bias, acc[qs][n][1] + bias);
        d.y = pack2(acc[qs][n][2] + bias, acc[qs][n][3] + bias);
        *(uint2*)&dst[rowv + t0] = d;
      }
    }
  } else {
    // Q/K/Qb/Kb: acc[pf][tf] -> row p = wv*32 + pf*16 + quad*4 + reg,
    // col t = tb + tf*16 + l16. h = wv; e = p & 31. Packed 8B stores.
    const int bmh = (b * Mn + m) * Hn + wv;
#pragma unroll
    for (int pf = 0; pf < 2; ++pf) {
      const int p0 = wv * 32 + pf * 16 + quad * 4;
      const float4 b4 = *(const float4*)&Bb[m * Pn + p0];
#pragma unroll
      for (int tf = 0; tf < 8; ++tf) {
        const int t = tb + tf * 16 + l16;
        float v0 = acc[pf][tf][0] + b4.x;
        float v1 = acc[pf][tf][1] + b4.y;
        float v2 = acc[pf][tf][2] + b4.z;
        float v3 = acc[pf][tf][3] + b4.w;
        if (doscale) { v0 *= SCALE; v1 *= SCALE; v2 *= SCALE; v3 *= SCALE; }
        uint2 d; d.x = pack2(v0, v1); d.y = pack2(v2, v3);
        *(uint2*)&dst[((size_t)bmh * Tn + t) * 32 + pf * 16 + quad * 4] = d;
      }
    }
  }
}

// ------------------------------------------------------- attention (flash) ---
// Wave-autonomous: wave = 32 q-rows of one (b,m,h). S^T = Khat.Qhat^T so C
// cols = q (lane&15): softmax = in-lane + xor16/xor32 shuffles; P written as
// packed 8B runs to a PRIVATE per-wave LDS slab (no __syncthreads anywhere);
// O^T = V^T.P keeps q on l16. K/Q/V frags load straight from global (L2).
// Load-balanced: each wave does the q-tile PAIR (j, 15-j) -> uniform 9
// key-chunk iterations per wave regardless of j.
__global__ __launch_bounds__(128, 4) void attn_flash(
    const u16* __restrict__ Qa, const u16* __restrict__ Ka,
    const u16* __restrict__ Qb, const u16* __restrict__ Kb,
    const u16* __restrict__ Vt, const int* __restrict__ lens,
    float* __restrict__ out) {
  __shared__ __align__(16) u16 Ps[2 * 32 * 72];  // 9.2KB, per-wave slabs

  const int tid = threadIdx.x;
  const int wv = tid >> 6, lane = tid & 63;
  const int quad = lane >> 4, l16 = lane & 15;

  const int wu = blockIdx.x * 2 + wv;      // 0..2047
  const int pair = wu & 7;                 // q-tile pair (pair, 15-pair)
  const int bmh = wu >> 3;
  const int b = bmh >> 6;                  // Mn*Hn = 64
  const int len = lens[b];

  const size_t rowbase = (size_t)bmh * Tn;
  const size_t vbase = (size_t)bmh * 32 * Tn;
  u16* myPs = &Ps[wv * 32 * 72];
  const int mm = (bmh >> 2) & (Mn - 1);
  const int h = bmh & (Hn - 1);

#pragma unroll 1
  for (int half = 0; half < 2; ++half) {
    const int qt = half ? (15 - pair) : pair;
    const int q0 = qt * 32;

    bf16x8 qf[2][2];
#pragma unroll
    for (int qs = 0; qs < 2; ++qs) {
      const size_t r = (rowbase + q0 + qs * 16 + l16) * 32 + quad * 8;
      qf[qs][0] = ld8(Qa + r);
      qf[qs][1] = ld8(Qb + r);
    }

    f32x4 O[2][2];  // [qs][es], D rows = e (quad*4+reg), cols = q (l16)
#pragma unroll
    for (int qs = 0; qs < 2; ++qs)
#pragma unroll
      for (int es = 0; es < 2; ++es) O[qs][es] = (f32x4){0.f, 0.f, 0.f, 0.f};
    float mrow[2] = {-1e30f, -1e30f}, lsum[2] = {0.f, 0.f};

    const int s_hi = min(q0 + 32, len);    // len >= T/2 >= 1
    for (int s0 = 0; s0 < s_hi; s0 += 64) {
      // S^T tiles: rows = keys (st*16 chunks), cols = q. Always 4 tiles
      // (loads stay in-bounds: s0+63 <= 511); masking handles validity.
      f32x4 S[2][4];
#pragma unroll
      for (int st = 0; st < 4; ++st) {
        const size_t kr = (rowbase + s0 + st * 16 + l16) * 32 + quad * 8;
        const bf16x8 k0 = ld8(Ka + kr);
        const bf16x8 k1 = ld8(Kb + kr);
#pragma unroll
        for (int qs = 0; qs < 2; ++qs)
          S[qs][st] = mfma16(k1, qf[qs][1],
                             mfma16(k0, qf[qs][0], (f32x4){0.f, 0.f, 0.f, 0.f}));
      }

#pragma unroll
      for (int qs = 0; qs < 2; ++qs) {
        const int q = q0 + qs * 16 + l16;
        const int qcap = min(q, len - 1);  // valid <=> s <= qcap
        const int sb = s0 + quad * 4;
        float cmax = -1e30f;
#pragma unroll
        for (int st = 0; st < 4; ++st)
#pragma unroll
          for (int reg = 0; reg < 4; ++reg) {
            const int s = sb + st * 16 + reg;
            const float v = (s <= qcap) ? S[qs][st][reg] : -1e30f;
            S[qs][st][reg] = v;
            cmax = fmaxf(cmax, v);
          }
        cmax = fmaxf(cmax, __shfl_xor(cmax, 16));
        cmax = fmaxf(cmax, __shfl_xor(cmax, 32));
        const float mnew = fmaxf(mrow[qs], cmax);  // finite: every chunk has a valid key
        const float alpha = __expf(mrow[qs] - mnew);
        mrow[qs] = mnew;
        float rsum = 0.f;
        u32 pk[4][2];
#pragma unroll
        for (int st = 0; st < 4; ++st) {
          const float p0 = __expf(S[qs][st][0] - mnew);
          const float p1 = __expf(S[qs][st][1] - mnew);
          const float p2 = __expf(S[qs][st][2] - mnew);
          const float p3 = __expf(S[qs][st][3] - mnew);
          rsum += (p0 + p1) + (p2 + p3);
          pk[st][0] = pack2(p0, p1);
          pk[st][1] = pack2(p2, p3);
        }
        rsum += __shfl_xor(rsum, 16);
        rsum += __shfl_xor(rsum, 32);
        lsum[qs] = lsum[qs] * alpha + rsum;
#pragma unroll
        for (int es = 0; es < 2; ++es)
#pragma unroll
          for (int reg = 0; reg < 4; ++reg) O[qs][es][reg] *= alpha;
        // P -> private LDS slab (8B packed runs; same-wave ordering via lgkmcnt)
#pragma unroll
        for (int st = 0; st < 4; ++st) {
          uint2 d; d.x = pk[st][0]; d.y = pk[st][1];
          *(uint2*)&myPs[(qs * 16 + l16) * 72 + st * 16 + quad * 4] = d;
        }
      }

      // O^T += V^T . P
#pragma unroll
      for (int kc = 0; kc < 2; ++kc) {
        const int ko = kc * 32 + quad * 8;
        const bf16x8 pf0 = ld8(&myPs[l16 * 72 + ko]);
        const bf16x8 pf1 = ld8(&myPs[(16 + l16) * 72 + ko]);
        const bf16x8 vf0 = ld8(Vt + vbase + (size_t)l16 * Tn + s0 + ko);
        const bf16x8 vf1 = ld8(Vt + vbase + (size_t)(16 + l16) * Tn + s0 + ko);
        O[0][0] = mfma16(vf0, pf0, O[0][0]);
        O[0][1] = mfma16(vf1, pf0, O[0][1]);
        O[1][0] = mfma16(vf0, pf1, O[1][0]);
        O[1][1] = mfma16(vf1, pf1, O[1][1]);
      }
    }

    // epilogue: lane q = qs*16+l16 (matches state), e = es*16+quad*4+reg
#pragma unroll
    for (int qs = 0; qs < 2; ++qs) {
      const float linv = 1.0f / lsum[qs];
      const int t = q0 + qs * 16 + l16;
      const size_t ob = (((size_t)b * Tn + t) * Mn + mm) * Pn + h * 32 + quad * 4;
#pragma unroll
      for (int es = 0; es < 2; ++es) {
        float4 o;
        o.x = O[qs][es][0] * linv; o.y = O[qs][es][1] * linv;
        o.z = O[qs][es][2] * linv; o.w = O[qs][es][3] * linv;
        *(float4*)&out[ob + es * 16] = o;
      }
    }
  }
}

// ------------------------------------------------------------------ launch ---
extern "C" void kernel_launch(void* const* d_in, const int* in_sizes, int n_in,
                              void* d_out, int out_size, void* d_ws, size_t ws_size,
                              hipStream_t stream) {
  const float* inp = (const float*)d_in[0];
  const float* pos = (const float*)d_in[1];
  const void* mask = d_in[2];
  const float* Wq  = (const float*)d_in[3];
  const float* Bq  = (const float*)d_in[4];
  const float* Wk  = (const float*)d_in[5];
  const float* Bk  = (const float*)d_in[6];
  const float* Wv  = (const float*)d_in[7];
  const float* Bv  = (const float*)d_in[8];
  const float* Wqt = (const float*)d_in[9];
  const float* Bqt = (const float*)d_in[10];
  const float* Wkt = (const float*)d_in[11];
  const float* Bkt = (const float*)d_in[12];
  float* out = (float*)d_out;

  const size_t nA = (size_t)Bn * Mn * Hn * Tn * 32;  // 4.19M elems per array
  u16* Qa = (u16*)d_ws;
  u16* Ka = Qa + nA;
  u16* Qb = Ka + nA;
  u16* Kb = Qb + nA;
  u16* Vt = Kb + nA;
  int* lens = (int*)(Vt + nA);
  u16* Xb = (u16*)(lens + 8);            // keep 16B alignment
  u16* Pb = Xb + (size_t)Bn * Tn * Mn * Dn;
  u16* Wb = Pb + (size_t)Bn * Tn * Dn;

  prep<<<1024, 256, 0, stream>>>(mask, inp, pos, Wq, Wk, Wv, Wqt, Wkt,
                                 lens, Xb, Pb, Wb);
  proj_mfma<<<(Bn * Tn / 128) * Mn * 5, 256, 0, stream>>>(
      Xb, Pb, Wb, Bq, Bk, Bv, Bqt, Bkt, Qa, Ka, Qb, Kb, Vt);
  attn_flash<<<(Bn * Mn * Hn * 8) / 2, 128, 0, stream>>>(
      Qa, Ka, Qb, Kb, Vt, lens, out);
}